// Round 8
// baseline (280.738 us; speedup 1.0000x reference)
//
#include <hip/hip_runtime.h>
#include <hip/hip_bf16.h>

#define D 128      // D_IN == D_OUT
#define SH 8       // log2 rows per bucket
#define BROWS 256  // rows per bucket
#define NBK_MAX 512
#define CH 8192    // edges per workgroup in k_pairs
#define CT 8       // col tiles (128/16)
#define KS 4       // k steps   (128/32)
#define NQ 4       // D quarters for the gather
#define QH 32      // halfs per quarter

typedef __bf16   bf16x8 __attribute__((ext_vector_type(8)));
typedef float    f32x4  __attribute__((ext_vector_type(4)));
typedef _Float16 f16x2  __attribute__((ext_vector_type(2)));
typedef _Float16 f16x4  __attribute__((ext_vector_type(4)));
typedef _Float16 f16x8  __attribute__((ext_vector_type(8)));

// ===========================================================================
// CSR build (bucketed)
// ===========================================================================
__global__ __launch_bounds__(256) void k_zero(int* __restrict__ p, int n) {
    for (int i = blockIdx.x * blockDim.x + threadIdx.x; i < n; i += gridDim.x * blockDim.x)
        p[i] = 0;
}

__global__ __launch_bounds__(256) void k_bucket_count(const int* __restrict__ rows,
                                                      int* __restrict__ bcnt, int E, int NBK) {
    __shared__ int h[NBK_MAX];
    for (int i = threadIdx.x; i < NBK; i += 256) h[i] = 0;
    __syncthreads();
    for (int e = blockIdx.x * blockDim.x + threadIdx.x; e < E; e += gridDim.x * blockDim.x)
        atomicAdd(&h[rows[e] >> SH], 1);
    __syncthreads();
    for (int i = threadIdx.x; i < NBK; i += 256) {
        int v = h[i];
        if (v) atomicAdd(&bcnt[i], v);
    }
}

__global__ __launch_bounds__(512) void k_scan_buckets(const int* __restrict__ bcnt,
                                                      int* __restrict__ boff,
                                                      int* __restrict__ bcur,
                                                      int* __restrict__ row_start,
                                                      int NBK, int N, int E) {
    __shared__ int sd[512];
    int t = threadIdx.x;
    int own = (t < NBK) ? bcnt[t] : 0;
    sd[t] = own;
    __syncthreads();
    for (int off = 1; off < 512; off <<= 1) {
        int add = (t >= off) ? sd[t - off] : 0;
        __syncthreads();
        sd[t] += add;
        __syncthreads();
    }
    if (t < NBK) {
        int ex = sd[t] - own;
        boff[t] = ex;
        bcur[t] = ex;
    }
    if (t == 0) {
        boff[NBK] = E;
        row_start[N] = E;
    }
}

__global__ __launch_bounds__(256) void k_pairs(const int* __restrict__ rows,
                                               const int* __restrict__ cols,
                                               int* __restrict__ bcur,
                                               unsigned* __restrict__ pairs, int E, int NBK) {
    __shared__ int h[NBK_MAX];
    int e0 = blockIdx.x * CH;
    if (e0 >= E) return;
    int e1 = min(E, e0 + CH);
    for (int i = threadIdx.x; i < NBK; i += 256) h[i] = 0;
    __syncthreads();
    for (int e = e0 + threadIdx.x; e < e1; e += 256)
        atomicAdd(&h[rows[e] >> SH], 1);
    __syncthreads();
    for (int b = threadIdx.x; b < NBK; b += 256) {
        int v = h[b];
        h[b] = v ? atomicAdd(&bcur[b], v) : 0;
    }
    __syncthreads();
    for (int e = e0 + threadIdx.x; e < e1; e += 256) {
        int r = rows[e];
        int b = r >> SH;
        int p = atomicAdd(&h[b], 1);
        pairs[p] = ((unsigned)(r & (BROWS - 1)) << 24) | (unsigned)cols[e];
    }
}

// per-bucket: hist -> scan -> row_start/dr -> place csr -> write quarter-major
// dr-scaled fp16 xh for this bucket's rows.  xh layout: [NQ][N][QH] halfs.
__global__ __launch_bounds__(256) void k_bucket_finish_x(const unsigned* __restrict__ pairs,
                                                         const int* __restrict__ boff,
                                                         const float* __restrict__ x,
                                                         int* __restrict__ row_start,
                                                         float* __restrict__ dr,
                                                         int* __restrict__ csr_col,
                                                         _Float16* __restrict__ xh, int N) {
    __shared__ int   h[BROWS];
    __shared__ int   cur[BROWS];
    __shared__ float drl[BROWS];
    int b = blockIdx.x;
    int t = threadIdx.x;
    int base = b << SH;
    int lim = min(N - base, BROWS);
    h[t] = 0;
    __syncthreads();
    int p0 = boff[b], p1 = boff[b + 1];
    for (int p = p0 + t; p < p1; p += 256)
        atomicAdd(&h[pairs[p] >> 24], 1);
    __syncthreads();
    int own = h[t];
    cur[t] = own;
    __syncthreads();
    for (int off = 1; off < 256; off <<= 1) {
        int add = (t >= off) ? cur[t - off] : 0;
        __syncthreads();
        cur[t] += add;
        __syncthreads();
    }
    int rs = p0 + cur[t] - own;      // global csr offset for row base+t
    float d = rsqrtf((float)(own + 1));
    drl[t] = d;
    if (t < lim) {
        row_start[base + t] = rs;
        dr[base + t] = d;
    }
    __syncthreads();
    cur[t] = rs;                     // becomes the place cursor
    __syncthreads();

    // quarter-major scaled fp16 write of this bucket's x rows
    for (int q = t * 4; q < lim * D; q += 256 * 4) {
        int row = q >> 7, d0 = q & 127;
        float4 v = *(const float4*)&x[(size_t)(base + row) * D + d0];
        float dd = drl[row];
        f16x4 hv = {(_Float16)(v.x * dd), (_Float16)(v.y * dd),
                    (_Float16)(v.z * dd), (_Float16)(v.w * dd)};
        *(f16x4*)&xh[((size_t)(d0 >> 5) * N + (base + row)) * QH + (d0 & 31)] = hv;
    }

    for (int p = p0 + t; p < p1; p += 256) {
        unsigned v = pairs[p];
        int q2 = atomicAdd(&cur[v >> 24], 1);
        csr_col[q2] = (int)(v & 0xFFFFFF);
    }
}

// ===========================================================================
// quartered gather (pass p): agg_q[r] = dr[r] * (xq[r] + sum_c xq[c])
// xq = xh + p*N*QH (6.4 MB working set -> L2-resident per XCD).
// Lane l: edge slot l>>4, half-pair (l&15)*2 of the 32-half quarter.
// One load instruction covers 4 edges (4 x 64B lines). Writes f16 agg into
// the first 256B of each 512B out-row slot (in-place, per-wave safe).
// ===========================================================================
__global__ __launch_bounds__(256) void k_gather_q(const int* __restrict__ row_start,
                                                  const int* __restrict__ csr_col,
                                                  const _Float16* __restrict__ xq,
                                                  const float* __restrict__ dr,
                                                  _Float16* __restrict__ aggh,
                                                  int N, int p) {
    int lane  = threadIdx.x & 63;
    int eslot = lane >> 4;
    int dpos  = (lane & 15) * 2;
    int gw = (blockIdx.x * blockDim.x + threadIdx.x) >> 6;
    int nw = (gridDim.x * blockDim.x) >> 6;
    for (int r = gw; r < N; r += nw) {
        int beg = row_start[r], end = row_start[r + 1];
        float drr = dr[r];
        f16x2 sv = *(const f16x2*)&xq[(size_t)r * QH + dpos];
        float a0 = (eslot == 0) ? (float)sv[0] : 0.f;
        float a1 = (eslot == 0) ? (float)sv[1] : 0.f;
        for (int cb = beg; cb < end; cb += 64) {
            int m = end - cb;
            if (m > 64) m = 64;
            int cidx = (lane < m) ? __builtin_nontemporal_load(&csr_col[cb + lane]) : 0;
            int g = 0;
            for (; g + 16 <= m; g += 16) {
                int c0 = __shfl(cidx, g + eslot);
                int c1 = __shfl(cidx, g + 4 + eslot);
                int c2 = __shfl(cidx, g + 8 + eslot);
                int c3 = __shfl(cidx, g + 12 + eslot);
                f16x2 p0 = *(const f16x2*)&xq[(size_t)c0 * QH + dpos];
                f16x2 p1 = *(const f16x2*)&xq[(size_t)c1 * QH + dpos];
                f16x2 p2 = *(const f16x2*)&xq[(size_t)c2 * QH + dpos];
                f16x2 p3 = *(const f16x2*)&xq[(size_t)c3 * QH + dpos];
                a0 += (float)p0[0] + (float)p1[0];
                a1 += (float)p0[1] + (float)p1[1];
                a0 += (float)p2[0] + (float)p3[0];
                a1 += (float)p2[1] + (float)p3[1];
            }
            for (; g < m; g += 4) {
                int srcl = g + eslot;
                bool valid = srcl < m;
                int c = __shfl(cidx, valid ? srcl : 0);
                if (valid) {
                    f16x2 pv = *(const f16x2*)&xq[(size_t)c * QH + dpos];
                    a0 += (float)pv[0];
                    a1 += (float)pv[1];
                }
            }
        }
        a0 += __shfl_xor(a0, 16);
        a1 += __shfl_xor(a1, 16);
        a0 += __shfl_xor(a0, 32);
        a1 += __shfl_xor(a1, 32);
        if (lane < 16) {
            f16x2 o = {(_Float16)(drr * a0), (_Float16)(drr * a1)};
            __builtin_nontemporal_store(o, (f16x2*)&aggh[(size_t)r * 256 + p * QH + dpos]);
        }
    }
}

// ===========================================================================
// projection + relu via f16 MFMA, reading f16 agg from out slots in place.
// out_row(fp32) = relu(agg_row(f16) @ W^T), W split f16 hi/lo (2 MFMAs).
// ===========================================================================
__global__ __launch_bounds__(256) void k_project_f16(const float* __restrict__ W,
                                                     float* __restrict__ out, int N) {
    __shared__ f16x8 Bhi[CT * KS * 64];   // 32 KB
    __shared__ f16x8 Blo[CT * KS * 64];   // 32 KB
    for (int f = threadIdx.x; f < CT * KS * 64; f += 256) {
        int l  = f & 63;
        int ks = (f >> 6) & 3;
        int ct = f >> 8;
        int o  = ct * 16 + (l & 15);
        int k0 = ks * 32 + ((l >> 4) * 8);
        const float* src = &W[o * D + k0];
        f16x8 hi, lo;
#pragma unroll
        for (int i = 0; i < 8; ++i) {
            float v = src[i];
            _Float16 h = (_Float16)v;
            hi[i] = h;
            lo[i] = (_Float16)(v - (float)h);
        }
        Bhi[f] = hi;
        Blo[f] = lo;
    }
    __syncthreads();

    const _Float16* ah = (const _Float16*)out;   // agg f16 lives in out slots
    int lane = threadIdx.x & 63;
    int wib  = threadIdx.x >> 6;
    int gw   = blockIdx.x * 4 + wib;
    int nw   = gridDim.x * 4;
    int nt   = N >> 4;
    int arow  = lane & 15;
    int kbase = (lane >> 4) * 8;

    for (int t = gw; t < nt; t += nw) {
        int row = t * 16 + arow;
        f16x8 A[KS];
#pragma unroll
        for (int ks = 0; ks < KS; ++ks)
            A[ks] = *(const f16x8*)&ah[(size_t)row * 256 + ks * 32 + kbase];

        f32x4 acc[CT];
#pragma unroll
        for (int ct = 0; ct < CT; ++ct) acc[ct] = (f32x4){0.f, 0.f, 0.f, 0.f};
#pragma unroll
        for (int ks = 0; ks < KS; ++ks) {
#pragma unroll
            for (int ct = 0; ct < CT; ++ct) {
                f16x8 bh = Bhi[(ct * KS + ks) * 64 + lane];
                f16x8 bl = Blo[(ct * KS + ks) * 64 + lane];
                acc[ct] = __builtin_amdgcn_mfma_f32_16x16x32_f16(A[ks], bh, acc[ct], 0, 0, 0);
                acc[ct] = __builtin_amdgcn_mfma_f32_16x16x32_f16(A[ks], bl, acc[ct], 0, 0, 0);
            }
        }
        int orow = t * 16 + (lane >> 4) * 4;
        int ocol = lane & 15;
#pragma unroll
        for (int ct = 0; ct < CT; ++ct) {
#pragma unroll
            for (int reg = 0; reg < 4; ++reg) {
                __builtin_nontemporal_store(fmaxf(acc[ct][reg], 0.f),
                                            &out[(size_t)(orow + reg) * D + ct * 16 + ocol]);
            }
        }
    }
}

// ===========================================================================
// mid-tier fallback: old bucket_finish (no xh) + fp32 gather + bf16 project
// ===========================================================================
__global__ __launch_bounds__(256) void k_bucket_finish(const unsigned* __restrict__ pairs,
                                                       const int* __restrict__ boff,
                                                       int* __restrict__ row_start,
                                                       float* __restrict__ dr,
                                                       int* __restrict__ csr_col, int N) {
    __shared__ int h[BROWS];
    __shared__ int cur[BROWS];
    int b = blockIdx.x;
    int t = threadIdx.x;
    int lim = min(N - (b << SH), BROWS);
    h[t] = 0;
    __syncthreads();
    int p0 = boff[b], p1 = boff[b + 1];
    for (int p = p0 + t; p < p1; p += 256)
        atomicAdd(&h[pairs[p] >> 24], 1);
    __syncthreads();
    int own = h[t];
    cur[t] = own;
    __syncthreads();
    for (int off = 1; off < 256; off <<= 1) {
        int add = (t >= off) ? cur[t - off] : 0;
        __syncthreads();
        cur[t] += add;
        __syncthreads();
    }
    int rs = p0 + cur[t] - own;
    if (t < lim) {
        row_start[(b << SH) + t] = rs;
        dr[(b << SH) + t] = rsqrtf((float)(own + 1));
    }
    __syncthreads();
    cur[t] = rs;
    __syncthreads();
    for (int p = p0 + t; p < p1; p += 256) {
        unsigned v = pairs[p];
        int q = atomicAdd(&cur[v >> 24], 1);
        csr_col[q] = (int)(v & 0xFFFFFF);
    }
}

__global__ __launch_bounds__(256) void k_gather(const int* __restrict__ row_start,
                                                const int* __restrict__ csr_col,
                                                const float* __restrict__ x,
                                                const float* __restrict__ dr,
                                                float* __restrict__ out, int N) {
    int lane = threadIdx.x & 63;
    int gw = (blockIdx.x * blockDim.x + threadIdx.x) >> 6;
    int nw = (gridDim.x * blockDim.x) >> 6;
    for (int r = gw; r < N; r += nw) {
        float drr = dr[r];
        int beg = row_start[r], end = row_start[r + 1];
        const float2 xs = *(const float2*)&x[(size_t)r * D + lane * 2];
        float s = drr * drr;
        float a0 = s * xs.x, a1 = s * xs.y;
        for (int cb = beg; cb < end; cb += 64) {
            int m = end - cb;
            if (m > 64) m = 64;
            int   cidx = (lane < m) ? csr_col[cb + lane] : 0;
            float cdr  = (lane < m) ? dr[cidx] : 0.f;
            int j = 0;
            for (; j + 4 <= m; j += 4) {
                int c0 = __shfl(cidx, j);
                int c1 = __shfl(cidx, j + 1);
                int c2 = __shfl(cidx, j + 2);
                int c3 = __shfl(cidx, j + 3);
                float v0 = drr * __shfl(cdr, j);
                float v1 = drr * __shfl(cdr, j + 1);
                float v2 = drr * __shfl(cdr, j + 2);
                float v3 = drr * __shfl(cdr, j + 3);
                const float2 p0 = *(const float2*)&x[(size_t)c0 * D + lane * 2];
                const float2 p1 = *(const float2*)&x[(size_t)c1 * D + lane * 2];
                const float2 p2 = *(const float2*)&x[(size_t)c2 * D + lane * 2];
                const float2 p3 = *(const float2*)&x[(size_t)c3 * D + lane * 2];
                a0 = fmaf(v0, p0.x, a0); a1 = fmaf(v0, p0.y, a1);
                a0 = fmaf(v1, p1.x, a0); a1 = fmaf(v1, p1.y, a1);
                a0 = fmaf(v2, p2.x, a0); a1 = fmaf(v2, p2.y, a1);
                a0 = fmaf(v3, p3.x, a0); a1 = fmaf(v3, p3.y, a1);
            }
            for (; j < m; ++j) {
                int   c = __shfl(cidx, j);
                float v = drr * __shfl(cdr, j);
                const float2 p = *(const float2*)&x[(size_t)c * D + lane * 2];
                a0 = fmaf(v, p.x, a0);
                a1 = fmaf(v, p.y, a1);
            }
        }
        float2 o;
        o.x = a0;
        o.y = a1;
        *(float2*)&out[(size_t)r * D + lane * 2] = o;
    }
}

__global__ __launch_bounds__(256) void k_project_mfma(const float* __restrict__ W,
                                                      float* __restrict__ out, int N) {
    __shared__ bf16x8 Bhi[CT * KS * 64];
    __shared__ bf16x8 Blo[CT * KS * 64];
    for (int f = threadIdx.x; f < CT * KS * 64; f += 256) {
        int l  = f & 63;
        int ks = (f >> 6) & 3;
        int ct = f >> 8;
        int o  = ct * 16 + (l & 15);
        int k0 = ks * 32 + ((l >> 4) * 8);
        const float* src = &W[o * D + k0];
        bf16x8 hi, lo;
#pragma unroll
        for (int i = 0; i < 8; ++i) {
            float v  = src[i];
            __bf16 h = (__bf16)v;
            hi[i] = h;
            lo[i] = (__bf16)(v - (float)h);
        }
        Bhi[f] = hi;
        Blo[f] = lo;
    }
    __syncthreads();

    int lane = threadIdx.x & 63;
    int wib  = threadIdx.x >> 6;
    int gw   = blockIdx.x * 4 + wib;
    int nw   = gridDim.x * 4;
    int nt   = N >> 4;
    int arow  = lane & 15;
    int kbase = (lane >> 4) * 8;

    for (int t = gw; t < nt; t += nw) {
        int row = t * 16 + arow;
        const float* arp = &out[(size_t)row * D + kbase];
        bf16x8 Ahi[KS], Alo[KS];
#pragma unroll
        for (int ks = 0; ks < KS; ++ks) {
            float4 v0 = *(const float4*)&arp[ks * 32];
            float4 v1 = *(const float4*)&arp[ks * 32 + 4];
            float va[8] = {v0.x, v0.y, v0.z, v0.w, v1.x, v1.y, v1.z, v1.w};
            bf16x8 hi, lo;
#pragma unroll
            for (int i = 0; i < 8; ++i) {
                __bf16 h = (__bf16)va[i];
                hi[i] = h;
                lo[i] = (__bf16)(va[i] - (float)h);
            }
            Ahi[ks] = hi;
            Alo[ks] = lo;
        }
        f32x4 acc[CT];
#pragma unroll
        for (int ct = 0; ct < CT; ++ct) acc[ct] = (f32x4){0.f, 0.f, 0.f, 0.f};
#pragma unroll
        for (int ks = 0; ks < KS; ++ks) {
#pragma unroll
            for (int ct = 0; ct < CT; ++ct) {
                bf16x8 bh = Bhi[(ct * KS + ks) * 64 + lane];
                bf16x8 bl = Blo[(ct * KS + ks) * 64 + lane];
                acc[ct] = __builtin_amdgcn_mfma_f32_16x16x32_bf16(Ahi[ks], bh, acc[ct], 0, 0, 0);
                acc[ct] = __builtin_amdgcn_mfma_f32_16x16x32_bf16(Alo[ks], bh, acc[ct], 0, 0, 0);
                acc[ct] = __builtin_amdgcn_mfma_f32_16x16x32_bf16(Ahi[ks], bl, acc[ct], 0, 0, 0);
            }
        }
        int orow = t * 16 + (lane >> 4) * 4;
        int ocol = lane & 15;
#pragma unroll
        for (int ct = 0; ct < CT; ++ct) {
#pragma unroll
            for (int reg = 0; reg < 4; ++reg) {
                out[(size_t)(orow + reg) * D + ct * 16 + ocol] = fmaxf(acc[ct][reg], 0.f);
            }
        }
    }
}

// ===========================================================================
// last-resort fallback (atomic path)
// ===========================================================================
__global__ __launch_bounds__(256) void k_init_deg(int* __restrict__ deg, int n) {
    for (int i = blockIdx.x * blockDim.x + threadIdx.x; i < n; i += gridDim.x * blockDim.x)
        deg[i] = 1;
}
__global__ __launch_bounds__(256) void k_count_atomic(const int* __restrict__ rows,
                                                      int* __restrict__ cnt, int E) {
    for (int e = blockIdx.x * blockDim.x + threadIdx.x; e < E; e += gridDim.x * blockDim.x)
        atomicAdd(&cnt[rows[e]], 1);
}
__global__ __launch_bounds__(256) void k_rsqrt(float* __restrict__ buf, int n) {
    const int* di = (const int*)buf;
    for (int i = blockIdx.x * blockDim.x + threadIdx.x; i < n; i += gridDim.x * blockDim.x) {
        int v = di[i];
        buf[i] = rsqrtf((float)v);
    }
}
__global__ __launch_bounds__(256) void k_init_out(const float4* __restrict__ x4,
                                                  const float* __restrict__ dr,
                                                  float4* __restrict__ out4, int n4) {
    for (int i = blockIdx.x * blockDim.x + threadIdx.x; i < n4; i += gridDim.x * blockDim.x) {
        float d = dr[i >> 5];
        float s = d * d;
        float4 v = x4[i];
        out4[i] = make_float4(v.x * s, v.y * s, v.z * s, v.w * s);
    }
}
__global__ __launch_bounds__(256) void k_edges(const int* __restrict__ rows,
                                               const int* __restrict__ cols,
                                               const float* __restrict__ x,
                                               const float* __restrict__ dr,
                                               float* __restrict__ out, int E) {
    int lane = threadIdx.x & 63;
    int wib  = threadIdx.x >> 6;
    int gw   = blockIdx.x * 4 + wib;
    int nw   = gridDim.x * 4;
    for (int e = gw; e < E; e += nw) {
        int r = rows[e];
        int c = cols[e];
        float val = dr[r] * dr[c];
        const float2 xv = *(const float2*)&x[(size_t)c * D + lane * 2];
        float* po = &out[(size_t)r * D + lane * 2];
        unsafeAtomicAdd(po,     val * xv.x);
        unsafeAtomicAdd(po + 1, val * xv.y);
    }
}

// ===========================================================================
extern "C" void kernel_launch(void* const* d_in, const int* in_sizes, int n_in,
                              void* d_out, int out_size, void* d_ws, size_t ws_size,
                              hipStream_t stream) {
    const float* x   = (const float*)d_in[0];
    const int*   idx = (const int*)d_in[1];
    const float* W   = (const float*)d_in[2];
    float*       out = (float*)d_out;

    int N = in_sizes[0] / D;   // 100000
    int E = in_sizes[1] / 2;   // 1.6M
    const int* rows = idx;
    const int* cols = idx + E;

    int NBK = (N + BROWS - 1) >> SH;   // 391

    // workspace layout in 4B words
    size_t off = 0;
    size_t o_pairs = off;  off += (size_t)E;
    size_t o_csr   = off;  off += (size_t)E;
    size_t o_rs    = off;  off += (size_t)N + 1;
    size_t o_dr    = off;  off += (size_t)N;
    size_t o_bcnt  = off;  off += (size_t)NBK;
    size_t o_boff  = off;  off += (size_t)NBK + 1;
    size_t o_bcur  = off;  off += (size_t)NBK;
    off = (off + 3) & ~(size_t)3;      // 16B align
    size_t need_mid = off * 4;
    size_t o_xh    = off;  off += ((size_t)N * D) / 2;   // NQ*N*QH halves
    size_t need_full = off * 4;

    int* wsw = (int*)d_ws;
    bool shape_ok = (NBK <= NBK_MAX) && ((N & 15) == 0) && (N < (1 << 24));

    if (shape_ok && ws_size >= need_mid) {
        unsigned* pairs     = (unsigned*)(wsw + o_pairs);
        int*      csr_col   = wsw + o_csr;
        int*      row_start = wsw + o_rs;
        float*    dr        = (float*)(wsw + o_dr);
        int*      bcnt      = wsw + o_bcnt;
        int*      boff      = wsw + o_boff;
        int*      bcur      = wsw + o_bcur;

        k_zero<<<(NBK + 255) / 256, 256, 0, stream>>>(bcnt, NBK);
        k_bucket_count<<<512, 256, 0, stream>>>(rows, bcnt, E, NBK);
        k_scan_buckets<<<1, 512, 0, stream>>>(bcnt, boff, bcur, row_start, NBK, N, E);
        k_pairs<<<(E + CH - 1) / CH, 256, 0, stream>>>(rows, cols, bcur, pairs, E, NBK);

        if (ws_size >= need_full) {
            _Float16* xh = (_Float16*)(wsw + o_xh);
            k_bucket_finish_x<<<NBK, 256, 0, stream>>>(pairs, boff, x, row_start, dr,
                                                       csr_col, xh, N);
            _Float16* aggh = (_Float16*)out;
            for (int p = 0; p < NQ; ++p) {
                const _Float16* xq = xh + (size_t)p * N * QH;
                k_gather_q<<<8192, 256, 0, stream>>>(row_start, csr_col, xq, dr, aggh, N, p);
            }
            int nt = N >> 4;
            k_project_f16<<<(nt + 3) / 4, 256, 0, stream>>>(W, out, N);
        } else {
            k_bucket_finish<<<NBK, 256, 0, stream>>>(pairs, boff, row_start, dr, csr_col, N);
            k_gather<<<4096, 256, 0, stream>>>(row_start, csr_col, x, dr, out, N);
            int nt = N >> 4;
            k_project_mfma<<<(nt + 3) / 4, 256, 0, stream>>>(W, out, N);
        }
    } else {
        int*   deg = (int*)d_ws;
        float* dr  = (float*)d_ws;
        k_init_deg<<<(N + 255) / 256, 256, 0, stream>>>(deg, N);
        k_count_atomic<<<2048, 256, 0, stream>>>(rows, deg, E);
        k_rsqrt<<<(N + 255) / 256, 256, 0, stream>>>(dr, N);
        int n4 = N * (D / 4);
        k_init_out<<<4096, 256, 0, stream>>>((const float4*)x, dr, (float4*)out, n4);
        k_edges<<<4096, 256, 0, stream>>>(rows, cols, x, dr, out, E);
        int nt = N >> 4;
        k_project_mfma<<<(nt + 3) / 4, 256, 0, stream>>>(W, out, N);
    }
}

// Round 9
// 202.880 us; speedup vs baseline: 1.3838x; 1.3838x over previous
//
#include <hip/hip_runtime.h>
#include <hip/hip_bf16.h>

#define D 128      // D_IN == D_OUT
#define SH 8       // log2 rows per bucket
#define BROWS 256  // rows per bucket
#define NBK_MAX 512
#define CH 8192    // edges per workgroup in k_pairs
#define CT 8       // col tiles (128/16)
#define KS 4       // k steps   (128/32)

typedef __bf16   bf16x8 __attribute__((ext_vector_type(8)));
typedef float    f32x4  __attribute__((ext_vector_type(4)));
typedef _Float16 f16x2  __attribute__((ext_vector_type(2)));
typedef _Float16 f16x4  __attribute__((ext_vector_type(4)));
typedef _Float16 f16x8  __attribute__((ext_vector_type(8)));

// ===========================================================================
// CSR build (bucketed)
// ===========================================================================
__global__ __launch_bounds__(256) void k_zero(int* __restrict__ p, int n) {
    for (int i = blockIdx.x * blockDim.x + threadIdx.x; i < n; i += gridDim.x * blockDim.x)
        p[i] = 0;
}

__global__ __launch_bounds__(256) void k_bucket_count(const int* __restrict__ rows,
                                                      int* __restrict__ bcnt, int E, int NBK) {
    __shared__ int h[NBK_MAX];
    for (int i = threadIdx.x; i < NBK; i += 256) h[i] = 0;
    __syncthreads();
    for (int e = blockIdx.x * blockDim.x + threadIdx.x; e < E; e += gridDim.x * blockDim.x)
        atomicAdd(&h[rows[e] >> SH], 1);
    __syncthreads();
    for (int i = threadIdx.x; i < NBK; i += 256) {
        int v = h[i];
        if (v) atomicAdd(&bcnt[i], v);
    }
}

__global__ __launch_bounds__(512) void k_scan_buckets(const int* __restrict__ bcnt,
                                                      int* __restrict__ boff,
                                                      int* __restrict__ bcur,
                                                      int* __restrict__ row_start,
                                                      int NBK, int N, int E) {
    __shared__ int sd[512];
    int t = threadIdx.x;
    int own = (t < NBK) ? bcnt[t] : 0;
    sd[t] = own;
    __syncthreads();
    for (int off = 1; off < 512; off <<= 1) {
        int add = (t >= off) ? sd[t - off] : 0;
        __syncthreads();
        sd[t] += add;
        __syncthreads();
    }
    if (t < NBK) {
        int ex = sd[t] - own;
        boff[t] = ex;
        bcur[t] = ex;
    }
    if (t == 0) {
        boff[NBK] = E;
        row_start[N] = E;
    }
}

__global__ __launch_bounds__(256) void k_pairs(const int* __restrict__ rows,
                                               const int* __restrict__ cols,
                                               int* __restrict__ bcur,
                                               unsigned* __restrict__ pairs, int E, int NBK) {
    __shared__ int h[NBK_MAX];
    int e0 = blockIdx.x * CH;
    if (e0 >= E) return;
    int e1 = min(E, e0 + CH);
    for (int i = threadIdx.x; i < NBK; i += 256) h[i] = 0;
    __syncthreads();
    for (int e = e0 + threadIdx.x; e < e1; e += 256)
        atomicAdd(&h[rows[e] >> SH], 1);
    __syncthreads();
    for (int b = threadIdx.x; b < NBK; b += 256) {
        int v = h[b];
        h[b] = v ? atomicAdd(&bcur[b], v) : 0;
    }
    __syncthreads();
    for (int e = e0 + threadIdx.x; e < e1; e += 256) {
        int r = rows[e];
        int b = r >> SH;
        int p = atomicAdd(&h[b], 1);
        pairs[p] = ((unsigned)(r & (BROWS - 1)) << 24) | (unsigned)cols[e];
    }
}

// per-bucket: hist -> scan -> row_start/dr -> place csr -> write ROW-major
// dr-scaled fp16 xh for this bucket's rows (fuses the old k_half_s pass).
__global__ __launch_bounds__(256) void k_bucket_finish_x(const unsigned* __restrict__ pairs,
                                                         const int* __restrict__ boff,
                                                         const float* __restrict__ x,
                                                         int* __restrict__ row_start,
                                                         float* __restrict__ dr,
                                                         int* __restrict__ csr_col,
                                                         _Float16* __restrict__ xh, int N) {
    __shared__ int   h[BROWS];
    __shared__ int   cur[BROWS];
    __shared__ float drl[BROWS];
    int b = blockIdx.x;
    int t = threadIdx.x;
    int base = b << SH;
    int lim = min(N - base, BROWS);
    h[t] = 0;
    __syncthreads();
    int p0 = boff[b], p1 = boff[b + 1];
    for (int p = p0 + t; p < p1; p += 256)
        atomicAdd(&h[pairs[p] >> 24], 1);
    __syncthreads();
    int own = h[t];
    cur[t] = own;
    __syncthreads();
    for (int off = 1; off < 256; off <<= 1) {
        int add = (t >= off) ? cur[t - off] : 0;
        __syncthreads();
        cur[t] += add;
        __syncthreads();
    }
    int rs = p0 + cur[t] - own;
    float d = rsqrtf((float)(own + 1));
    drl[t] = d;
    if (t < lim) {
        row_start[base + t] = rs;
        dr[base + t] = d;
    }
    __syncthreads();
    cur[t] = rs;
    __syncthreads();

    // row-major scaled fp16 write of this bucket's x rows
    for (int q = t * 4; q < lim * D; q += 256 * 4) {
        int row = q >> 7, d0 = q & 127;
        float4 v = *(const float4*)&x[(size_t)(base + row) * D + d0];
        float dd = drl[row];
        f16x4 hv = {(_Float16)(v.x * dd), (_Float16)(v.y * dd),
                    (_Float16)(v.z * dd), (_Float16)(v.w * dd)};
        *(f16x4*)&xh[(size_t)(base + row) * D + d0] = hv;
    }

    for (int p = p0 + t; p < p1; p += 256) {
        unsigned v = pairs[p];
        int q2 = atomicAdd(&cur[v >> 24], 1);
        csr_col[q2] = (int)(v & 0xFFFFFF);
    }
}

// W -> f16 hi/lo fragment arrays (MFMA fragment order) in global ws
__global__ __launch_bounds__(256) void k_prepW(const float* __restrict__ W,
                                               f16x8* __restrict__ Whi,
                                               f16x8* __restrict__ Wlo) {
    for (int f = blockIdx.x * blockDim.x + threadIdx.x; f < CT * KS * 64;
         f += gridDim.x * blockDim.x) {
        int l  = f & 63;
        int ks = (f >> 6) & 3;
        int ct = f >> 8;
        int o  = ct * 16 + (l & 15);
        int k0 = ks * 32 + ((l >> 4) * 8);
        const float* src = &W[o * D + k0];
        f16x8 hi, lo;
#pragma unroll
        for (int i = 0; i < 8; ++i) {
            float v = src[i];
            _Float16 h = (_Float16)v;
            hi[i] = h;
            lo[i] = (_Float16)(v - (float)h);
        }
        Whi[f] = hi;
        Wlo[f] = lo;
    }
}

// ===========================================================================
// gather (round-7 proven structure): agg_f16[r] = dr[r]*(xh'[r] + sum xh'[c])
// one wave per row; lane covers 2 halfs; 8 edges unrolled; 24 VGPR.
// Writes f16 agg into the first 256 B of each 512 B out-row slot.
// ===========================================================================
__global__ __launch_bounds__(256) void k_gather_s(const int* __restrict__ row_start,
                                                  const int* __restrict__ csr_col,
                                                  const _Float16* __restrict__ xh,
                                                  const float* __restrict__ dr,
                                                  _Float16* __restrict__ aggh, int N) {
    int lane = threadIdx.x & 63;
    int gw = (blockIdx.x * blockDim.x + threadIdx.x) >> 6;
    int nw = (gridDim.x * blockDim.x) >> 6;
    for (int r = gw; r < N; r += nw) {
        float drr = dr[r];
        int beg = row_start[r], end = row_start[r + 1];
        const f16x2 xs = *(const f16x2*)&xh[(size_t)r * D + lane * 2];
        float a0 = (float)xs[0], a1 = (float)xs[1];
        for (int cb = beg; cb < end; cb += 64) {
            int m = end - cb;
            if (m > 64) m = 64;
            int cidx = (lane < m) ? csr_col[cb + lane] : 0;
            int j = 0;
            for (; j + 8 <= m; j += 8) {
                int c0 = __shfl(cidx, j);
                int c1 = __shfl(cidx, j + 1);
                int c2 = __shfl(cidx, j + 2);
                int c3 = __shfl(cidx, j + 3);
                int c4 = __shfl(cidx, j + 4);
                int c5 = __shfl(cidx, j + 5);
                int c6 = __shfl(cidx, j + 6);
                int c7 = __shfl(cidx, j + 7);
                f16x2 p0 = *(const f16x2*)&xh[(size_t)c0 * D + lane * 2];
                f16x2 p1 = *(const f16x2*)&xh[(size_t)c1 * D + lane * 2];
                f16x2 p2 = *(const f16x2*)&xh[(size_t)c2 * D + lane * 2];
                f16x2 p3 = *(const f16x2*)&xh[(size_t)c3 * D + lane * 2];
                f16x2 p4 = *(const f16x2*)&xh[(size_t)c4 * D + lane * 2];
                f16x2 p5 = *(const f16x2*)&xh[(size_t)c5 * D + lane * 2];
                f16x2 p6 = *(const f16x2*)&xh[(size_t)c6 * D + lane * 2];
                f16x2 p7 = *(const f16x2*)&xh[(size_t)c7 * D + lane * 2];
                a0 += (float)p0[0] + (float)p1[0] + (float)p2[0] + (float)p3[0]
                    + (float)p4[0] + (float)p5[0] + (float)p6[0] + (float)p7[0];
                a1 += (float)p0[1] + (float)p1[1] + (float)p2[1] + (float)p3[1]
                    + (float)p4[1] + (float)p5[1] + (float)p6[1] + (float)p7[1];
            }
            for (; j < m; ++j) {
                int c = __shfl(cidx, j);
                f16x2 p = *(const f16x2*)&xh[(size_t)c * D + lane * 2];
                a0 += (float)p[0];
                a1 += (float)p[1];
            }
        }
        f16x2 o = {(_Float16)(drr * a0), (_Float16)(drr * a1)};
        *(f16x2*)&aggh[(size_t)r * 256 + lane * 2] = o;
    }
}

// ===========================================================================
// projection + relu: f16 MFMA, A (f16 agg) from out slots, B (W frags f16
// hi/lo) from GLOBAL (L1/L2-hot 64 KB) -- no LDS -> high occupancy.
// ===========================================================================
__global__ __launch_bounds__(256) void k_project_g(const f16x8* __restrict__ Whi,
                                                   const f16x8* __restrict__ Wlo,
                                                   float* __restrict__ out, int N) {
    const _Float16* ah = (const _Float16*)out;
    int lane = threadIdx.x & 63;
    int wib  = threadIdx.x >> 6;
    int gw   = blockIdx.x * 4 + wib;
    int nw   = gridDim.x * 4;
    int nt   = N >> 4;
    int arow  = lane & 15;
    int kbase = (lane >> 4) * 8;

    for (int t = gw; t < nt; t += nw) {
        int row = t * 16 + arow;
        f16x8 A[KS];
#pragma unroll
        for (int ks = 0; ks < KS; ++ks)
            A[ks] = *(const f16x8*)&ah[(size_t)row * 256 + ks * 32 + kbase];

        f32x4 acc[CT];
#pragma unroll
        for (int ct = 0; ct < CT; ++ct) acc[ct] = (f32x4){0.f, 0.f, 0.f, 0.f};
#pragma unroll
        for (int ks = 0; ks < KS; ++ks) {
#pragma unroll
            for (int ct = 0; ct < CT; ++ct) {
                f16x8 bh = Whi[(ct * KS + ks) * 64 + lane];
                f16x8 bl = Wlo[(ct * KS + ks) * 64 + lane];
                acc[ct] = __builtin_amdgcn_mfma_f32_16x16x32_f16(A[ks], bh, acc[ct], 0, 0, 0);
                acc[ct] = __builtin_amdgcn_mfma_f32_16x16x32_f16(A[ks], bl, acc[ct], 0, 0, 0);
            }
        }
        int orow = t * 16 + (lane >> 4) * 4;
        int ocol = lane & 15;
#pragma unroll
        for (int ct = 0; ct < CT; ++ct) {
#pragma unroll
            for (int reg = 0; reg < 4; ++reg) {
                out[(size_t)(orow + reg) * D + ct * 16 + ocol] = fmaxf(acc[ct][reg], 0.f);
            }
        }
    }
}

// ===========================================================================
// mid-tier fallback: plain bucket_finish + fp32 gather + LDS bf16 project
// ===========================================================================
__global__ __launch_bounds__(256) void k_bucket_finish(const unsigned* __restrict__ pairs,
                                                       const int* __restrict__ boff,
                                                       int* __restrict__ row_start,
                                                       float* __restrict__ dr,
                                                       int* __restrict__ csr_col, int N) {
    __shared__ int h[BROWS];
    __shared__ int cur[BROWS];
    int b = blockIdx.x;
    int t = threadIdx.x;
    int lim = min(N - (b << SH), BROWS);
    h[t] = 0;
    __syncthreads();
    int p0 = boff[b], p1 = boff[b + 1];
    for (int p = p0 + t; p < p1; p += 256)
        atomicAdd(&h[pairs[p] >> 24], 1);
    __syncthreads();
    int own = h[t];
    cur[t] = own;
    __syncthreads();
    for (int off = 1; off < 256; off <<= 1) {
        int add = (t >= off) ? cur[t - off] : 0;
        __syncthreads();
        cur[t] += add;
        __syncthreads();
    }
    int rs = p0 + cur[t] - own;
    if (t < lim) {
        row_start[(b << SH) + t] = rs;
        dr[(b << SH) + t] = rsqrtf((float)(own + 1));
    }
    __syncthreads();
    cur[t] = rs;
    __syncthreads();
    for (int p = p0 + t; p < p1; p += 256) {
        unsigned v = pairs[p];
        int q = atomicAdd(&cur[v >> 24], 1);
        csr_col[q] = (int)(v & 0xFFFFFF);
    }
}

__global__ __launch_bounds__(256) void k_gather(const int* __restrict__ row_start,
                                                const int* __restrict__ csr_col,
                                                const float* __restrict__ x,
                                                const float* __restrict__ dr,
                                                float* __restrict__ out, int N) {
    int lane = threadIdx.x & 63;
    int gw = (blockIdx.x * blockDim.x + threadIdx.x) >> 6;
    int nw = (gridDim.x * blockDim.x) >> 6;
    for (int r = gw; r < N; r += nw) {
        float drr = dr[r];
        int beg = row_start[r], end = row_start[r + 1];
        const float2 xs = *(const float2*)&x[(size_t)r * D + lane * 2];
        float s = drr * drr;
        float a0 = s * xs.x, a1 = s * xs.y;
        for (int cb = beg; cb < end; cb += 64) {
            int m = end - cb;
            if (m > 64) m = 64;
            int   cidx = (lane < m) ? csr_col[cb + lane] : 0;
            float cdr  = (lane < m) ? dr[cidx] : 0.f;
            int j = 0;
            for (; j + 4 <= m; j += 4) {
                int c0 = __shfl(cidx, j);
                int c1 = __shfl(cidx, j + 1);
                int c2 = __shfl(cidx, j + 2);
                int c3 = __shfl(cidx, j + 3);
                float v0 = drr * __shfl(cdr, j);
                float v1 = drr * __shfl(cdr, j + 1);
                float v2 = drr * __shfl(cdr, j + 2);
                float v3 = drr * __shfl(cdr, j + 3);
                const float2 p0 = *(const float2*)&x[(size_t)c0 * D + lane * 2];
                const float2 p1 = *(const float2*)&x[(size_t)c1 * D + lane * 2];
                const float2 p2 = *(const float2*)&x[(size_t)c2 * D + lane * 2];
                const float2 p3 = *(const float2*)&x[(size_t)c3 * D + lane * 2];
                a0 = fmaf(v0, p0.x, a0); a1 = fmaf(v0, p0.y, a1);
                a0 = fmaf(v1, p1.x, a0); a1 = fmaf(v1, p1.y, a1);
                a0 = fmaf(v2, p2.x, a0); a1 = fmaf(v2, p2.y, a1);
                a0 = fmaf(v3, p3.x, a0); a1 = fmaf(v3, p3.y, a1);
            }
            for (; j < m; ++j) {
                int   c = __shfl(cidx, j);
                float v = drr * __shfl(cdr, j);
                const float2 p = *(const float2*)&x[(size_t)c * D + lane * 2];
                a0 = fmaf(v, p.x, a0);
                a1 = fmaf(v, p.y, a1);
            }
        }
        float2 o;
        o.x = a0;
        o.y = a1;
        *(float2*)&out[(size_t)r * D + lane * 2] = o;
    }
}

__global__ __launch_bounds__(256) void k_project_mfma(const float* __restrict__ W,
                                                      float* __restrict__ out, int N) {
    __shared__ bf16x8 Bhi[CT * KS * 64];
    __shared__ bf16x8 Blo[CT * KS * 64];
    for (int f = threadIdx.x; f < CT * KS * 64; f += 256) {
        int l  = f & 63;
        int ks = (f >> 6) & 3;
        int ct = f >> 8;
        int o  = ct * 16 + (l & 15);
        int k0 = ks * 32 + ((l >> 4) * 8);
        const float* src = &W[o * D + k0];
        bf16x8 hi, lo;
#pragma unroll
        for (int i = 0; i < 8; ++i) {
            float v  = src[i];
            __bf16 h = (__bf16)v;
            hi[i] = h;
            lo[i] = (__bf16)(v - (float)h);
        }
        Bhi[f] = hi;
        Blo[f] = lo;
    }
    __syncthreads();

    int lane = threadIdx.x & 63;
    int wib  = threadIdx.x >> 6;
    int gw   = blockIdx.x * 4 + wib;
    int nw   = gridDim.x * 4;
    int nt   = N >> 4;
    int arow  = lane & 15;
    int kbase = (lane >> 4) * 8;

    for (int t = gw; t < nt; t += nw) {
        int row = t * 16 + arow;
        const float* arp = &out[(size_t)row * D + kbase];
        bf16x8 Ahi[KS], Alo[KS];
#pragma unroll
        for (int ks = 0; ks < KS; ++ks) {
            float4 v0 = *(const float4*)&arp[ks * 32];
            float4 v1 = *(const float4*)&arp[ks * 32 + 4];
            float va[8] = {v0.x, v0.y, v0.z, v0.w, v1.x, v1.y, v1.z, v1.w};
            bf16x8 hi, lo;
#pragma unroll
            for (int i = 0; i < 8; ++i) {
                __bf16 h = (__bf16)va[i];
                hi[i] = h;
                lo[i] = (__bf16)(va[i] - (float)h);
            }
            Ahi[ks] = hi;
            Alo[ks] = lo;
        }
        f32x4 acc[CT];
#pragma unroll
        for (int ct = 0; ct < CT; ++ct) acc[ct] = (f32x4){0.f, 0.f, 0.f, 0.f};
#pragma unroll
        for (int ks = 0; ks < KS; ++ks) {
#pragma unroll
            for (int ct = 0; ct < CT; ++ct) {
                bf16x8 bh = Bhi[(ct * KS + ks) * 64 + lane];
                bf16x8 bl = Blo[(ct * KS + ks) * 64 + lane];
                acc[ct] = __builtin_amdgcn_mfma_f32_16x16x32_bf16(Ahi[ks], bh, acc[ct], 0, 0, 0);
                acc[ct] = __builtin_amdgcn_mfma_f32_16x16x32_bf16(Alo[ks], bh, acc[ct], 0, 0, 0);
                acc[ct] = __builtin_amdgcn_mfma_f32_16x16x32_bf16(Ahi[ks], bl, acc[ct], 0, 0, 0);
            }
        }
        int orow = t * 16 + (lane >> 4) * 4;
        int ocol = lane & 15;
#pragma unroll
        for (int ct = 0; ct < CT; ++ct) {
#pragma unroll
            for (int reg = 0; reg < 4; ++reg) {
                out[(size_t)(orow + reg) * D + ct * 16 + ocol] = fmaxf(acc[ct][reg], 0.f);
            }
        }
    }
}

// ===========================================================================
// last-resort fallback (atomic path)
// ===========================================================================
__global__ __launch_bounds__(256) void k_init_deg(int* __restrict__ deg, int n) {
    for (int i = blockIdx.x * blockDim.x + threadIdx.x; i < n; i += gridDim.x * blockDim.x)
        deg[i] = 1;
}
__global__ __launch_bounds__(256) void k_count_atomic(const int* __restrict__ rows,
                                                      int* __restrict__ cnt, int E) {
    for (int e = blockIdx.x * blockDim.x + threadIdx.x; e < E; e += gridDim.x * blockDim.x)
        atomicAdd(&cnt[rows[e]], 1);
}
__global__ __launch_bounds__(256) void k_rsqrt(float* __restrict__ buf, int n) {
    const int* di = (const int*)buf;
    for (int i = blockIdx.x * blockDim.x + threadIdx.x; i < n; i += gridDim.x * blockDim.x) {
        int v = di[i];
        buf[i] = rsqrtf((float)v);
    }
}
__global__ __launch_bounds__(256) void k_init_out(const float4* __restrict__ x4,
                                                  const float* __restrict__ dr,
                                                  float4* __restrict__ out4, int n4) {
    for (int i = blockIdx.x * blockDim.x + threadIdx.x; i < n4; i += gridDim.x * blockDim.x) {
        float d = dr[i >> 5];
        float s = d * d;
        float4 v = x4[i];
        out4[i] = make_float4(v.x * s, v.y * s, v.z * s, v.w * s);
    }
}
__global__ __launch_bounds__(256) void k_edges(const int* __restrict__ rows,
                                               const int* __restrict__ cols,
                                               const float* __restrict__ x,
                                               const float* __restrict__ dr,
                                               float* __restrict__ out, int E) {
    int lane = threadIdx.x & 63;
    int wib  = threadIdx.x >> 6;
    int gw   = blockIdx.x * 4 + wib;
    int nw   = gridDim.x * 4;
    for (int e = gw; e < E; e += nw) {
        int r = rows[e];
        int c = cols[e];
        float val = dr[r] * dr[c];
        const float2 xv = *(const float2*)&x[(size_t)c * D + lane * 2];
        float* po = &out[(size_t)r * D + lane * 2];
        unsafeAtomicAdd(po,     val * xv.x);
        unsafeAtomicAdd(po + 1, val * xv.y);
    }
}

// ===========================================================================
extern "C" void kernel_launch(void* const* d_in, const int* in_sizes, int n_in,
                              void* d_out, int out_size, void* d_ws, size_t ws_size,
                              hipStream_t stream) {
    const float* x   = (const float*)d_in[0];
    const int*   idx = (const int*)d_in[1];
    const float* W   = (const float*)d_in[2];
    float*       out = (float*)d_out;

    int N = in_sizes[0] / D;   // 100000
    int E = in_sizes[1] / 2;   // 1.6M
    const int* rows = idx;
    const int* cols = idx + E;

    int NBK = (N + BROWS - 1) >> SH;   // 391

    // workspace layout in 4B words
    size_t off = 0;
    size_t o_pairs = off;  off += (size_t)E;
    size_t o_csr   = off;  off += (size_t)E;
    size_t o_rs    = off;  off += (size_t)N + 1;
    size_t o_dr    = off;  off += (size_t)N;
    size_t o_bcnt  = off;  off += (size_t)NBK;
    size_t o_boff  = off;  off += (size_t)NBK + 1;
    size_t o_bcur  = off;  off += (size_t)NBK;
    off = (off + 3) & ~(size_t)3;      // 16B align
    size_t need_mid = off * 4;
    size_t o_whi   = off;  off += (size_t)(CT * KS * 64) * 4;   // f16x8 = 4 words
    size_t o_wlo   = off;  off += (size_t)(CT * KS * 64) * 4;
    size_t o_xh    = off;  off += ((size_t)N * D) / 2;          // halves = words/2
    size_t need_full = off * 4;

    int* wsw = (int*)d_ws;
    bool shape_ok = (NBK <= NBK_MAX) && ((N & 15) == 0) && (N < (1 << 24));

    if (shape_ok && ws_size >= need_mid) {
        unsigned* pairs     = (unsigned*)(wsw + o_pairs);
        int*      csr_col   = wsw + o_csr;
        int*      row_start = wsw + o_rs;
        float*    dr        = (float*)(wsw + o_dr);
        int*      bcnt      = wsw + o_bcnt;
        int*      boff      = wsw + o_boff;
        int*      bcur      = wsw + o_bcur;

        k_zero<<<(NBK + 255) / 256, 256, 0, stream>>>(bcnt, NBK);
        k_bucket_count<<<512, 256, 0, stream>>>(rows, bcnt, E, NBK);
        k_scan_buckets<<<1, 512, 0, stream>>>(bcnt, boff, bcur, row_start, NBK, N, E);
        k_pairs<<<(E + CH - 1) / CH, 256, 0, stream>>>(rows, cols, bcur, pairs, E, NBK);

        if (ws_size >= need_full) {
            f16x8*    Whi = (f16x8*)(wsw + o_whi);
            f16x8*    Wlo = (f16x8*)(wsw + o_wlo);
            _Float16* xh  = (_Float16*)(wsw + o_xh);
            k_bucket_finish_x<<<NBK, 256, 0, stream>>>(pairs, boff, x, row_start, dr,
                                                       csr_col, xh, N);
            k_prepW<<<8, 256, 0, stream>>>(W, Whi, Wlo);
            _Float16* aggh = (_Float16*)out;
            k_gather_s<<<4096, 256, 0, stream>>>(row_start, csr_col, xh, dr, aggh, N);
            int nt = N >> 4;
            k_project_g<<<(nt + 3) / 4, 256, 0, stream>>>(Whi, Wlo, out, N);
        } else {
            k_bucket_finish<<<NBK, 256, 0, stream>>>(pairs, boff, row_start, dr, csr_col, N);
            k_gather<<<4096, 256, 0, stream>>>(row_start, csr_col, x, dr, out, N);
            int nt = N >> 4;
            k_project_mfma<<<(nt + 3) / 4, 256, 0, stream>>>(W, out, N);
        }
    } else {
        int*   deg = (int*)d_ws;
        float* dr  = (float*)d_ws;
        k_init_deg<<<(N + 255) / 256, 256, 0, stream>>>(deg, N);
        k_count_atomic<<<2048, 256, 0, stream>>>(rows, deg, E);
        k_rsqrt<<<(N + 255) / 256, 256, 0, stream>>>(dr, N);
        int n4 = N * (D / 4);
        k_init_out<<<4096, 256, 0, stream>>>((const float4*)x, dr, (float4*)out, n4);
        k_edges<<<4096, 256, 0, stream>>>(rows, cols, x, dr, out, E);
        int nt = N >> 4;
        k_project_mfma<<<(nt + 3) / 4, 256, 0, stream>>>(W, out, N);
    }
}

// Round 10
// 193.901 us; speedup vs baseline: 1.4478x; 1.0463x over previous
//
#include <hip/hip_runtime.h>
#include <hip/hip_bf16.h>

#define D 128      // D_IN == D_OUT
#define SH 8       // log2 rows per bucket
#define BROWS 256  // rows per bucket
#define NBK_MAX 512
#define CT 8       // col tiles (128/16)
#define KS 4       // k steps   (128/32)

typedef __bf16   bf16x8 __attribute__((ext_vector_type(8)));
typedef float    f32x4  __attribute__((ext_vector_type(4)));
typedef _Float16 f16x2  __attribute__((ext_vector_type(2)));
typedef _Float16 f16x4  __attribute__((ext_vector_type(4)));
typedef _Float16 f16x8  __attribute__((ext_vector_type(8)));

// ===========================================================================
// CSR build (bucketed)
// ===========================================================================
__global__ __launch_bounds__(256) void k_zero(int* __restrict__ p, int n) {
    for (int i = blockIdx.x * blockDim.x + threadIdx.x; i < n; i += gridDim.x * blockDim.x)
        p[i] = 0;
}

__global__ __launch_bounds__(256) void k_bucket_count(const int* __restrict__ rows,
                                                      int* __restrict__ bcnt, int E, int NBK) {
    __shared__ int h[NBK_MAX];
    for (int i = threadIdx.x; i < NBK; i += 256) h[i] = 0;
    __syncthreads();
    for (int e = blockIdx.x * blockDim.x + threadIdx.x; e < E; e += gridDim.x * blockDim.x)
        atomicAdd(&h[rows[e] >> SH], 1);
    __syncthreads();
    for (int i = threadIdx.x; i < NBK; i += 256) {
        int v = h[i];
        if (v) atomicAdd(&bcnt[i], v);
    }
}

__global__ __launch_bounds__(512) void k_scan_buckets(const int* __restrict__ bcnt,
                                                      int* __restrict__ boff,
                                                      int* __restrict__ bcur,
                                                      int* __restrict__ row_start,
                                                      int NBK, int N, int E) {
    __shared__ int sd[512];
    int t = threadIdx.x;
    int own = (t < NBK) ? bcnt[t] : 0;
    sd[t] = own;
    __syncthreads();
    for (int off = 1; off < 512; off <<= 1) {
        int add = (t >= off) ? sd[t - off] : 0;
        __syncthreads();
        sd[t] += add;
        __syncthreads();
    }
    if (t < NBK) {
        int ex = sd[t] - own;
        boff[t] = ex;
        bcur[t] = ex;
    }
    if (t == 0) {
        boff[NBK] = E;
        row_start[N] = E;
    }
}

// chunk size is a runtime arg now (smaller chunk -> more WGs -> more overlap)
__global__ __launch_bounds__(256) void k_pairs(const int* __restrict__ rows,
                                               const int* __restrict__ cols,
                                               int* __restrict__ bcur,
                                               unsigned* __restrict__ pairs,
                                               int E, int NBK, int chunk) {
    __shared__ int h[NBK_MAX];
    int e0 = blockIdx.x * chunk;
    if (e0 >= E) return;
    int e1 = min(E, e0 + chunk);
    for (int i = threadIdx.x; i < NBK; i += 256) h[i] = 0;
    __syncthreads();
    for (int e = e0 + threadIdx.x; e < e1; e += 256)
        atomicAdd(&h[rows[e] >> SH], 1);
    __syncthreads();
    for (int b = threadIdx.x; b < NBK; b += 256) {
        int v = h[b];
        h[b] = v ? atomicAdd(&bcur[b], v) : 0;
    }
    __syncthreads();
    for (int e = e0 + threadIdx.x; e < e1; e += 256) {
        int r = rows[e];
        int b = r >> SH;
        int p = atomicAdd(&h[b], 1);
        pairs[p] = ((unsigned)(r & (BROWS - 1)) << 24) | (unsigned)cols[e];
    }
}

// per-bucket: hist -> scan -> row_start/dr -> place csr (no x conversion)
__global__ __launch_bounds__(256) void k_bucket_finish(const unsigned* __restrict__ pairs,
                                                       const int* __restrict__ boff,
                                                       int* __restrict__ row_start,
                                                       float* __restrict__ dr,
                                                       int* __restrict__ csr_col, int N) {
    __shared__ int h[BROWS];
    __shared__ int cur[BROWS];
    int b = blockIdx.x;
    int t = threadIdx.x;
    int lim = min(N - (b << SH), BROWS);
    h[t] = 0;
    __syncthreads();
    int p0 = boff[b], p1 = boff[b + 1];
    for (int p = p0 + t; p < p1; p += 256)
        atomicAdd(&h[pairs[p] >> 24], 1);
    __syncthreads();
    int own = h[t];
    cur[t] = own;
    __syncthreads();
    for (int off = 1; off < 256; off <<= 1) {
        int add = (t >= off) ? cur[t - off] : 0;
        __syncthreads();
        cur[t] += add;
        __syncthreads();
    }
    int rs = p0 + cur[t] - own;
    if (t < lim) {
        row_start[(b << SH) + t] = rs;
        dr[(b << SH) + t] = rsqrtf((float)(own + 1));
    }
    __syncthreads();
    cur[t] = rs;
    __syncthreads();
    for (int p = p0 + t; p < p1; p += 256) {
        unsigned v = pairs[p];
        int q = atomicAdd(&cur[v >> 24], 1);
        csr_col[q] = (int)(v & 0xFFFFFF);
    }
}

// x (fp32) -> xh (fp16), pre-scaled by dr (high-grid streaming kernel)
__global__ __launch_bounds__(256) void k_half_s(const float4* __restrict__ x4,
                                                const float* __restrict__ dr,
                                                f16x4* __restrict__ xh4, int n4) {
    for (int i = blockIdx.x * blockDim.x + threadIdx.x; i < n4; i += gridDim.x * blockDim.x) {
        float d = dr[i >> 5];   // 32 float4 per row
        float4 v = x4[i];
        xh4[i] = (f16x4){(_Float16)(v.x * d), (_Float16)(v.y * d),
                         (_Float16)(v.z * d), (_Float16)(v.w * d)};
    }
}

// W -> f16 fragment array (MFMA fragment order) in global ws (hi only)
__global__ __launch_bounds__(256) void k_prepW(const float* __restrict__ W,
                                               f16x8* __restrict__ Whi) {
    for (int f = blockIdx.x * blockDim.x + threadIdx.x; f < CT * KS * 64;
         f += gridDim.x * blockDim.x) {
        int l  = f & 63;
        int ks = (f >> 6) & 3;
        int ct = f >> 8;
        int o  = ct * 16 + (l & 15);
        int k0 = ks * 32 + ((l >> 4) * 8);
        const float* src = &W[o * D + k0];
        f16x8 hi;
#pragma unroll
        for (int i = 0; i < 8; ++i) hi[i] = (_Float16)src[i];
        Whi[f] = hi;
    }
}

// ===========================================================================
// gather (proven): agg_f16[r] = dr[r]*(xh'[r] + sum xh'[c]); 24 VGPR.
// Writes f16 agg into the first 256 B of each 512 B out-row slot.
// ===========================================================================
__global__ __launch_bounds__(256) void k_gather_s(const int* __restrict__ row_start,
                                                  const int* __restrict__ csr_col,
                                                  const _Float16* __restrict__ xh,
                                                  const float* __restrict__ dr,
                                                  _Float16* __restrict__ aggh, int N) {
    int lane = threadIdx.x & 63;
    int gw = (blockIdx.x * blockDim.x + threadIdx.x) >> 6;
    int nw = (gridDim.x * blockDim.x) >> 6;
    for (int r = gw; r < N; r += nw) {
        float drr = dr[r];
        int beg = row_start[r], end = row_start[r + 1];
        const f16x2 xs = *(const f16x2*)&xh[(size_t)r * D + lane * 2];
        float a0 = (float)xs[0], a1 = (float)xs[1];
        for (int cb = beg; cb < end; cb += 64) {
            int m = end - cb;
            if (m > 64) m = 64;
            int cidx = (lane < m) ? csr_col[cb + lane] : 0;
            int j = 0;
            for (; j + 8 <= m; j += 8) {
                int c0 = __shfl(cidx, j);
                int c1 = __shfl(cidx, j + 1);
                int c2 = __shfl(cidx, j + 2);
                int c3 = __shfl(cidx, j + 3);
                int c4 = __shfl(cidx, j + 4);
                int c5 = __shfl(cidx, j + 5);
                int c6 = __shfl(cidx, j + 6);
                int c7 = __shfl(cidx, j + 7);
                f16x2 p0 = *(const f16x2*)&xh[(size_t)c0 * D + lane * 2];
                f16x2 p1 = *(const f16x2*)&xh[(size_t)c1 * D + lane * 2];
                f16x2 p2 = *(const f16x2*)&xh[(size_t)c2 * D + lane * 2];
                f16x2 p3 = *(const f16x2*)&xh[(size_t)c3 * D + lane * 2];
                f16x2 p4 = *(const f16x2*)&xh[(size_t)c4 * D + lane * 2];
                f16x2 p5 = *(const f16x2*)&xh[(size_t)c5 * D + lane * 2];
                f16x2 p6 = *(const f16x2*)&xh[(size_t)c6 * D + lane * 2];
                f16x2 p7 = *(const f16x2*)&xh[(size_t)c7 * D + lane * 2];
                a0 += (float)p0[0] + (float)p1[0] + (float)p2[0] + (float)p3[0]
                    + (float)p4[0] + (float)p5[0] + (float)p6[0] + (float)p7[0];
                a1 += (float)p0[1] + (float)p1[1] + (float)p2[1] + (float)p3[1]
                    + (float)p4[1] + (float)p5[1] + (float)p6[1] + (float)p7[1];
            }
            for (; j < m; ++j) {
                int c = __shfl(cidx, j);
                f16x2 p = *(const f16x2*)&xh[(size_t)c * D + lane * 2];
                a0 += (float)p[0];
                a1 += (float)p[1];
            }
        }
        f16x2 o = {(_Float16)(drr * a0), (_Float16)(drr * a1)};
        *(f16x2*)&aggh[(size_t)r * 256 + lane * 2] = o;
    }
}

// ===========================================================================
// projection + relu: f16 MFMA (W single-f16), A from out slots, B from
// global L2-hot 32 KB; no LDS -> high occupancy. 32 MFMA / 16-row tile.
// ===========================================================================
__global__ __launch_bounds__(256) void k_project_g(const f16x8* __restrict__ Whi,
                                                   float* __restrict__ out, int N) {
    const _Float16* ah = (const _Float16*)out;
    int lane = threadIdx.x & 63;
    int wib  = threadIdx.x >> 6;
    int gw   = blockIdx.x * 4 + wib;
    int nw   = gridDim.x * 4;
    int nt   = N >> 4;
    int arow  = lane & 15;
    int kbase = (lane >> 4) * 8;

    for (int t = gw; t < nt; t += nw) {
        int row = t * 16 + arow;
        f16x8 A[KS];
#pragma unroll
        for (int ks = 0; ks < KS; ++ks)
            A[ks] = *(const f16x8*)&ah[(size_t)row * 256 + ks * 32 + kbase];

        f32x4 acc[CT];
#pragma unroll
        for (int ct = 0; ct < CT; ++ct) acc[ct] = (f32x4){0.f, 0.f, 0.f, 0.f};
#pragma unroll
        for (int ks = 0; ks < KS; ++ks) {
#pragma unroll
            for (int ct = 0; ct < CT; ++ct) {
                f16x8 bh = Whi[(ct * KS + ks) * 64 + lane];
                acc[ct] = __builtin_amdgcn_mfma_f32_16x16x32_f16(A[ks], bh, acc[ct], 0, 0, 0);
            }
        }
        int orow = t * 16 + (lane >> 4) * 4;
        int ocol = lane & 15;
#pragma unroll
        for (int ct = 0; ct < CT; ++ct) {
#pragma unroll
            for (int reg = 0; reg < 4; ++reg) {
                out[(size_t)(orow + reg) * D + ct * 16 + ocol] = fmaxf(acc[ct][reg], 0.f);
            }
        }
    }
}

// ===========================================================================
// mid-tier fallback: fp32 gather + LDS bf16-split project
// ===========================================================================
__global__ __launch_bounds__(256) void k_gather(const int* __restrict__ row_start,
                                                const int* __restrict__ csr_col,
                                                const float* __restrict__ x,
                                                const float* __restrict__ dr,
                                                float* __restrict__ out, int N) {
    int lane = threadIdx.x & 63;
    int gw = (blockIdx.x * blockDim.x + threadIdx.x) >> 6;
    int nw = (gridDim.x * blockDim.x) >> 6;
    for (int r = gw; r < N; r += nw) {
        float drr = dr[r];
        int beg = row_start[r], end = row_start[r + 1];
        const float2 xs = *(const float2*)&x[(size_t)r * D + lane * 2];
        float s = drr * drr;
        float a0 = s * xs.x, a1 = s * xs.y;
        for (int cb = beg; cb < end; cb += 64) {
            int m = end - cb;
            if (m > 64) m = 64;
            int   cidx = (lane < m) ? csr_col[cb + lane] : 0;
            float cdr  = (lane < m) ? dr[cidx] : 0.f;
            int j = 0;
            for (; j + 4 <= m; j += 4) {
                int c0 = __shfl(cidx, j);
                int c1 = __shfl(cidx, j + 1);
                int c2 = __shfl(cidx, j + 2);
                int c3 = __shfl(cidx, j + 3);
                float v0 = drr * __shfl(cdr, j);
                float v1 = drr * __shfl(cdr, j + 1);
                float v2 = drr * __shfl(cdr, j + 2);
                float v3 = drr * __shfl(cdr, j + 3);
                const float2 p0 = *(const float2*)&x[(size_t)c0 * D + lane * 2];
                const float2 p1 = *(const float2*)&x[(size_t)c1 * D + lane * 2];
                const float2 p2 = *(const float2*)&x[(size_t)c2 * D + lane * 2];
                const float2 p3 = *(const float2*)&x[(size_t)c3 * D + lane * 2];
                a0 = fmaf(v0, p0.x, a0); a1 = fmaf(v0, p0.y, a1);
                a0 = fmaf(v1, p1.x, a0); a1 = fmaf(v1, p1.y, a1);
                a0 = fmaf(v2, p2.x, a0); a1 = fmaf(v2, p2.y, a1);
                a0 = fmaf(v3, p3.x, a0); a1 = fmaf(v3, p3.y, a1);
            }
            for (; j < m; ++j) {
                int   c = __shfl(cidx, j);
                float v = drr * __shfl(cdr, j);
                const float2 p = *(const float2*)&x[(size_t)c * D + lane * 2];
                a0 = fmaf(v, p.x, a0);
                a1 = fmaf(v, p.y, a1);
            }
        }
        float2 o;
        o.x = a0;
        o.y = a1;
        *(float2*)&out[(size_t)r * D + lane * 2] = o;
    }
}

__global__ __launch_bounds__(256) void k_project_mfma(const float* __restrict__ W,
                                                      float* __restrict__ out, int N) {
    __shared__ bf16x8 Bhi[CT * KS * 64];
    __shared__ bf16x8 Blo[CT * KS * 64];
    for (int f = threadIdx.x; f < CT * KS * 64; f += 256) {
        int l  = f & 63;
        int ks = (f >> 6) & 3;
        int ct = f >> 8;
        int o  = ct * 16 + (l & 15);
        int k0 = ks * 32 + ((l >> 4) * 8);
        const float* src = &W[o * D + k0];
        bf16x8 hi, lo;
#pragma unroll
        for (int i = 0; i < 8; ++i) {
            float v  = src[i];
            __bf16 h = (__bf16)v;
            hi[i] = h;
            lo[i] = (__bf16)(v - (float)h);
        }
        Bhi[f] = hi;
        Blo[f] = lo;
    }
    __syncthreads();

    int lane = threadIdx.x & 63;
    int wib  = threadIdx.x >> 6;
    int gw   = blockIdx.x * 4 + wib;
    int nw   = gridDim.x * 4;
    int nt   = N >> 4;
    int arow  = lane & 15;
    int kbase = (lane >> 4) * 8;

    for (int t = gw; t < nt; t += nw) {
        int row = t * 16 + arow;
        const float* arp = &out[(size_t)row * D + kbase];
        bf16x8 Ahi[KS], Alo[KS];
#pragma unroll
        for (int ks = 0; ks < KS; ++ks) {
            float4 v0 = *(const float4*)&arp[ks * 32];
            float4 v1 = *(const float4*)&arp[ks * 32 + 4];
            float va[8] = {v0.x, v0.y, v0.z, v0.w, v1.x, v1.y, v1.z, v1.w};
            bf16x8 hi, lo;
#pragma unroll
            for (int i = 0; i < 8; ++i) {
                __bf16 h = (__bf16)va[i];
                hi[i] = h;
                lo[i] = (__bf16)(va[i] - (float)h);
            }
            Ahi[ks] = hi;
            Alo[ks] = lo;
        }
        f32x4 acc[CT];
#pragma unroll
        for (int ct = 0; ct < CT; ++ct) acc[ct] = (f32x4){0.f, 0.f, 0.f, 0.f};
#pragma unroll
        for (int ks = 0; ks < KS; ++ks) {
#pragma unroll
            for (int ct = 0; ct < CT; ++ct) {
                bf16x8 bh = Bhi[(ct * KS + ks) * 64 + lane];
                bf16x8 bl = Blo[(ct * KS + ks) * 64 + lane];
                acc[ct] = __builtin_amdgcn_mfma_f32_16x16x32_bf16(Ahi[ks], bh, acc[ct], 0, 0, 0);
                acc[ct] = __builtin_amdgcn_mfma_f32_16x16x32_bf16(Alo[ks], bh, acc[ct], 0, 0, 0);
                acc[ct] = __builtin_amdgcn_mfma_f32_16x16x32_bf16(Ahi[ks], bl, acc[ct], 0, 0, 0);
            }
        }
        int orow = t * 16 + (lane >> 4) * 4;
        int ocol = lane & 15;
#pragma unroll
        for (int ct = 0; ct < CT; ++ct) {
#pragma unroll
            for (int reg = 0; reg < 4; ++reg) {
                out[(size_t)(orow + reg) * D + ct * 16 + ocol] = fmaxf(acc[ct][reg], 0.f);
            }
        }
    }
}

// ===========================================================================
// last-resort fallback (atomic path)
// ===========================================================================
__global__ __launch_bounds__(256) void k_init_deg(int* __restrict__ deg, int n) {
    for (int i = blockIdx.x * blockDim.x + threadIdx.x; i < n; i += gridDim.x * blockDim.x)
        deg[i] = 1;
}
__global__ __launch_bounds__(256) void k_count_atomic(const int* __restrict__ rows,
                                                      int* __restrict__ cnt, int E) {
    for (int e = blockIdx.x * blockDim.x + threadIdx.x; e < E; e += gridDim.x * blockDim.x)
        atomicAdd(&cnt[rows[e]], 1);
}
__global__ __launch_bounds__(256) void k_rsqrt(float* __restrict__ buf, int n) {
    const int* di = (const int*)buf;
    for (int i = blockIdx.x * blockDim.x + threadIdx.x; i < n; i += gridDim.x * blockDim.x) {
        int v = di[i];
        buf[i] = rsqrtf((float)v);
    }
}
__global__ __launch_bounds__(256) void k_init_out(const float4* __restrict__ x4,
                                                  const float* __restrict__ dr,
                                                  float4* __restrict__ out4, int n4) {
    for (int i = blockIdx.x * blockDim.x + threadIdx.x; i < n4; i += gridDim.x * blockDim.x) {
        float d = dr[i >> 5];
        float s = d * d;
        float4 v = x4[i];
        out4[i] = make_float4(v.x * s, v.y * s, v.z * s, v.w * s);
    }
}
__global__ __launch_bounds__(256) void k_edges(const int* __restrict__ rows,
                                               const int* __restrict__ cols,
                                               const float* __restrict__ x,
                                               const float* __restrict__ dr,
                                               float* __restrict__ out, int E) {
    int lane = threadIdx.x & 63;
    int wib  = threadIdx.x >> 6;
    int gw   = blockIdx.x * 4 + wib;
    int nw   = gridDim.x * 4;
    for (int e = gw; e < E; e += nw) {
        int r = rows[e];
        int c = cols[e];
        float val = dr[r] * dr[c];
        const float2 xv = *(const float2*)&x[(size_t)c * D + lane * 2];
        float* po = &out[(size_t)r * D + lane * 2];
        unsafeAtomicAdd(po,     val * xv.x);
        unsafeAtomicAdd(po + 1, val * xv.y);
    }
}

// ===========================================================================
extern "C" void kernel_launch(void* const* d_in, const int* in_sizes, int n_in,
                              void* d_out, int out_size, void* d_ws, size_t ws_size,
                              hipStream_t stream) {
    const float* x   = (const float*)d_in[0];
    const int*   idx = (const int*)d_in[1];
    const float* W   = (const float*)d_in[2];
    float*       out = (float*)d_out;

    int N = in_sizes[0] / D;   // 100000
    int E = in_sizes[1] / 2;   // 1.6M
    const int* rows = idx;
    const int* cols = idx + E;

    int NBK = (N + BROWS - 1) >> SH;   // 391

    // workspace layout in 4B words
    size_t off = 0;
    size_t o_pairs = off;  off += (size_t)E;
    size_t o_csr   = off;  off += (size_t)E;
    size_t o_rs    = off;  off += (size_t)N + 1;
    size_t o_dr    = off;  off += (size_t)N;
    size_t o_bcnt  = off;  off += (size_t)NBK;
    size_t o_boff  = off;  off += (size_t)NBK + 1;
    size_t o_bcur  = off;  off += (size_t)NBK;
    off = (off + 3) & ~(size_t)3;      // 16B align
    size_t need_mid = off * 4;
    size_t o_whi   = off;  off += (size_t)(CT * KS * 64) * 4;   // f16x8 = 4 words
    size_t o_xh    = off;  off += ((size_t)N * D) / 2;          // halves = words/2
    size_t need_full = off * 4;

    int* wsw = (int*)d_ws;
    bool shape_ok = (NBK <= NBK_MAX) && ((N & 15) == 0) && (N < (1 << 24));

    if (shape_ok && ws_size >= need_mid) {
        unsigned* pairs     = (unsigned*)(wsw + o_pairs);
        int*      csr_col   = wsw + o_csr;
        int*      row_start = wsw + o_rs;
        float*    dr        = (float*)(wsw + o_dr);
        int*      bcnt      = wsw + o_bcnt;
        int*      boff      = wsw + o_boff;
        int*      bcur      = wsw + o_bcur;

        const int CHUNK = 2048;        // 782 WGs in k_pairs
        k_zero<<<(NBK + 255) / 256, 256, 0, stream>>>(bcnt, NBK);
        k_bucket_count<<<512, 256, 0, stream>>>(rows, bcnt, E, NBK);
        k_scan_buckets<<<1, 512, 0, stream>>>(bcnt, boff, bcur, row_start, NBK, N, E);
        k_pairs<<<(E + CHUNK - 1) / CHUNK, 256, 0, stream>>>(rows, cols, bcur, pairs,
                                                             E, NBK, CHUNK);
        k_bucket_finish<<<NBK, 256, 0, stream>>>(pairs, boff, row_start, dr, csr_col, N);

        if (ws_size >= need_full) {
            f16x8*    Whi = (f16x8*)(wsw + o_whi);
            _Float16* xh  = (_Float16*)(wsw + o_xh);
            k_half_s<<<2048, 256, 0, stream>>>((const float4*)x, dr, (f16x4*)xh, N * (D / 4));
            k_prepW<<<8, 256, 0, stream>>>(W, Whi);
            _Float16* aggh = (_Float16*)out;
            k_gather_s<<<4096, 256, 0, stream>>>(row_start, csr_col, xh, dr, aggh, N);
            int nt = N >> 4;
            k_project_g<<<(nt + 3) / 4, 256, 0, stream>>>(Whi, out, N);
        } else {
            k_gather<<<4096, 256, 0, stream>>>(row_start, csr_col, x, dr, out, N);
            int nt = N >> 4;
            k_project_mfma<<<(nt + 3) / 4, 256, 0, stream>>>(W, out, N);
        }
    } else {
        int*   deg = (int*)d_ws;
        float* dr  = (float*)d_ws;
        k_init_deg<<<(N + 255) / 256, 256, 0, stream>>>(deg, N);
        k_count_atomic<<<2048, 256, 0, stream>>>(rows, deg, E);
        k_rsqrt<<<(N + 255) / 256, 256, 0, stream>>>(dr, N);
        int n4 = N * (D / 4);
        k_init_out<<<4096, 256, 0, stream>>>((const float4*)x, dr, (float4*)out, n4);
        k_edges<<<4096, 256, 0, stream>>>(rows, cols, x, dr, out, E);
        int nt = N >> 4;
        k_project_mfma<<<(nt + 3) / 4, 256, 0, stream>>>(W, out, N);
    }
}